// Round 19
// baseline (245.146 us; speedup 1.0000x reference)
//
#include <hip/hip_runtime.h>
#include <hip/hip_bf16.h>

typedef unsigned short ushort;
typedef unsigned long long u64;
typedef short bf16x8 __attribute__((ext_vector_type(8)));
typedef _Float16 f16x8 __attribute__((ext_vector_type(8)));
typedef float f32x4 __attribute__((ext_vector_type(4)));

#define NB 8
#define SS 2048
#define DD 768
#define DKV 214
#define DKP 224
#define WROWS 256
#define MSHIFT 40.0f

__device__ __forceinline__ float bf2f(ushort u) {
  union { unsigned int i; float f; } v; v.i = ((unsigned int)u) << 16; return v.f;
}
__device__ __forceinline__ ushort f2bf(float f) {
  union { float f; unsigned int i; } v; v.f = f;
  unsigned int x = v.i;
  return (ushort)((x + 0x7fffu + ((x >> 16) & 1u)) >> 16);
}
__device__ __forceinline__ ushort f2h(float f) {
  union { _Float16 h; ushort u; } cv; cv.h = (_Float16)f; return cv.u;
}
__device__ __forceinline__ bf16x8 cvt8v(f32x4 a, f32x4 b) {
  bf16x8 r;
#pragma unroll
  for (int j = 0; j < 4; ++j) { r[j] = (short)f2bf(a[j]); r[j + 4] = (short)f2bf(b[j]); }
  return r;
}
__device__ __forceinline__ f16x8 cvt8h(f32x4 a, f32x4 b) {
  f16x8 r;
#pragma unroll
  for (int j = 0; j < 4; ++j) { r[j] = (_Float16)a[j]; r[j + 4] = (_Float16)b[j]; }
  return r;
}
// async global->LDS, 16B per lane; LDS dest is wave-uniform base + lane*16
__device__ __forceinline__ void gload16(const void* g, void* l) {
  __builtin_amdgcn_global_load_lds(
      (const __attribute__((address_space(1))) void*)g,
      (__attribute__((address_space(3))) void*)l, 16, 0, 0);
}

// ---- prep_w: Z zero + weight packing only (precedes projections; tiny) ----
__global__ __launch_bounds__(256)
void prep_w(const float* __restrict__ Wq, const float* __restrict__ Wk,
            const float* __restrict__ Wv, ushort* __restrict__ Wqp,
            ushort* __restrict__ Wkp, ushort* __restrict__ Wvb,
            float* __restrict__ Z)
{
  const int tid0 = blockIdx.x * 256 + threadIdx.x;
  const int stride = gridDim.x * 256;
  for (int i = tid0; i < NB * SS; i += stride) Z[i] = 0.f;
  const int NW = WROWS * DD;
  const int NV = DD * DD;
  for (int i = tid0; i < 2 * NW + NV; i += stride) {
    if (i < NW) {
      int r = i / DD, c = i % DD;
      float v = (r < DKV) ? Wq[i] : 0.f;
      Wqp[(c >> 5) * (WROWS * 32) + r * 32 + (c & 31)] = f2h(v);
    } else if (i < 2 * NW) {
      int j = i - NW;
      int r = j / DD, c = j % DD;
      float v = (r < DKV) ? Wk[j] : 0.f;
      Wkp[(c >> 5) * (WROWS * 32) + r * 32 + (c & 31)] = f2h(v);
    } else {
      int j = i - 2 * NW;
      int r = j / DD, c = j % DD;
      Wvb[(c >> 5) * (DD * 32) + r * 32 + (c & 31)] = f2bf(Wv[j]);
    }
  }
}

// ---- fused_proj: blocks [0,768) = V projection; [768,1280) = Q/K projection;
// [1280,1792) = dmask->dbits scan (pure BW; dispatches last -> fills tails).
// Bodies verbatim from R18; only blockIdx decode differs.
__global__ __launch_bounds__(256, 3)
void fused_proj(const float* __restrict__ x1, const float* __restrict__ x2,
                const float* __restrict__ x3,
                const ushort* __restrict__ Wqp, const ushort* __restrict__ Wkp,
                const ushort* __restrict__ Wvb,
                const float* __restrict__ bq, const float* __restrict__ bk,
                const float* __restrict__ bv, const float* __restrict__ dmk,
                ushort* __restrict__ Qp, ushort* __restrict__ Kp,
                ushort* __restrict__ Vp, u64* __restrict__ dbits)
{
  __shared__ __align__(16) char smem[36864];
  const int bid = blockIdx.x;
  const int tid = threadIdx.x;
  const int w  = tid >> 6;
  const int l  = tid & 63;
  const int lr = l & 15;
  const int lh = l >> 4;

  if (bid >= 1280) {
    // ---- dmask -> dbits (ballot-native: word q of chunk holds bit l = elem 4l+q) ----
    const int db = bid - 1280;
    const size_t wv = (size_t)db * 4 + w;
    const size_t nw = 512 * 4;
    const size_t nchunks = (size_t)NB * SS * SS / 256;
    for (size_t c = wv; c < nchunks; c += nw) {
      f32x4 v = *(const f32x4*)(dmk + c * 256 + 4 * l);
      u64 b0 = __ballot(v[0] > 0.5f);
      u64 b1 = __ballot(v[1] > 0.5f);
      u64 b2 = __ballot(v[2] > 0.5f);
      u64 b3 = __ballot(v[3] > 0.5f);
      if (l == 0) {
        u64* d = dbits + c * 4;
        d[0] = b0; d[1] = b1; d[2] = b2; d[3] = b3;
      }
    }
    return;
  }

  const int srow = (w << 4) + (l >> 2);
  const size_t gc = (size_t)srow * 64 + (size_t)((((l & 3) ^ ((srow >> 1) & 3))) << 4);
  const f32x4 fzero = {0.f, 0.f, 0.f, 0.f};

  if (bid >= 768) {
    // ---- Q/K projection: 64m x 224n, wave = 16m x 224n, acc[14], dbuf slab ----
    const int b2 = bid - 768;
    const int m0 = (b2 & 255) * 64;
    const int which = b2 >> 8;
    const float*  A    = which ? x2 : x1;
    const ushort* Bw   = which ? Wkp : Wqp;
    const float*  bias = which ? bk : bq;
    ushort* Cp = which ? Kp : Qp;

    typedef char QBuf[256][64];
    QBuf* lds = (QBuf*)smem;                    // lds[2][256][64] = 32 KB
    const char* gb = (const char*)Bw;

    f32x4 acc[14];
#pragma unroll
    for (int nt = 0; nt < 14; ++nt) acc[nt] = fzero;

    const float* arow = A + (size_t)(m0 + w * 16 + lr) * DD + lh * 8;

#define QKSTAGE(buf, kk) do {                                             \
    size_t ko = (size_t)(kk) * (WROWS * 64);                              \
    gload16(gb + ko + gc,         &lds[buf][w << 4][0]);                  \
    gload16(gb + ko + gc + 4096,  &lds[buf][(w << 4) + 64][0]);           \
    gload16(gb + ko + gc + 8192,  &lds[buf][(w << 4) + 128][0]);          \
    gload16(gb + ko + gc + 12288, &lds[buf][(w << 4) + 192][0]);          \
  } while (0)

    QKSTAGE(0, 0);
    f32x4 pa = *(const f32x4*)(arow);
    f32x4 pb = *(const f32x4*)(arow + 4);
    __syncthreads();

    for (int kk = 0; kk < 24; ++kk) {
      const int buf = kk & 1;
      if (kk < 23) QKSTAGE(buf ^ 1, kk + 1);
      f32x4 na = fzero, nb = fzero;
      if (kk < 23) {
        na = *(const f32x4*)(arow + (kk + 1) * 32);
        nb = *(const f32x4*)(arow + (kk + 1) * 32 + 4);
      }
      f16x8 af = cvt8h(pa, pb);
#pragma unroll
      for (int nt = 0; nt < 14; ++nt) {
        int br = nt * 16 + lr;
        int bo = (lh ^ ((br >> 1) & 3)) << 4;
        f16x8 wf = *(const f16x8*)&lds[buf][br][bo];
        acc[nt] = __builtin_amdgcn_mfma_f32_16x16x32_f16(af, wf, acc[nt], 0, 0, 0);
      }
      __syncthreads();
      pa = na; pb = nb;
    }
#undef QKSTAGE

#pragma unroll
    for (int nt = 0; nt < 14; ++nt) {
      int n = nt * 16 + lr;                   // < 224 by construction
      float bv2 = (n < DKV) ? bias[n] : 0.f;
#pragma unroll
      for (int r = 0; r < 4; ++r) {
        int m = m0 + w * 16 + lh * 4 + r;
        int bb = m >> 11, s = m & 2047;
        float val = (n < DKV) ? (acc[nt][r] + bv2) : 0.f;
        Cp[((size_t)(bb * 7 + (n >> 5)) * SS + s) * 32 + (n & 31)] = f2h(val);
      }
    }
    return;
  }

  // ---- V projection: 64m x 256n, wave = 16m x 256n, acc[16], dbuf + lt union ----
  {
    const int m0 = (bid & 255) * 64;
    const int n0 = (bid >> 8) * 256;

    typedef char VBuf[256][64];
    VBuf* stage = (VBuf*)smem;
    ushort (*lt)[72] = (ushort(*)[72])smem;

    const char* gvw = (const char*)Wvb + (size_t)n0 * 64;

    f32x4 acc[16];
#pragma unroll
    for (int nt = 0; nt < 16; ++nt) acc[nt] = fzero;

    const float* arow = x3 + (size_t)(m0 + w * 16 + lr) * DD + lh * 8;

#define VSTAGE(buf, kk) do {                                              \
    size_t ko = (size_t)(kk) * (DD * 64);                                 \
    gload16(gvw + ko + gc,         &stage[buf][w << 4][0]);               \
    gload16(gvw + ko + gc + 4096,  &stage[buf][(w << 4) + 64][0]);        \
    gload16(gvw + ko + gc + 8192,  &stage[buf][(w << 4) + 128][0]);       \
    gload16(gvw + ko + gc + 12288, &stage[buf][(w << 4) + 192][0]);       \
  } while (0)

    VSTAGE(0, 0);
    f32x4 pa = *(const f32x4*)(arow);
    f32x4 pb = *(const f32x4*)(arow + 4);
    __syncthreads();

    for (int kk = 0; kk < 24; ++kk) {
      const int buf = kk & 1;
      if (kk < 23) VSTAGE(buf ^ 1, kk + 1);
      f32x4 na = fzero, nb = fzero;
      if (kk < 23) {
        na = *(const f32x4*)(arow + (kk + 1) * 32);
        nb = *(const f32x4*)(arow + (kk + 1) * 32 + 4);
      }
      bf16x8 af = cvt8v(pa, pb);
#pragma unroll
      for (int nt = 0; nt < 16; ++nt) {
        int br = nt * 16 + lr;
        int bo = (lh ^ ((br >> 1) & 3)) << 4;
        bf16x8 bfr = *(const bf16x8*)&stage[buf][br][bo];
        acc[nt] = __builtin_amdgcn_mfma_f32_16x16x32_bf16(af, bfr, acc[nt], 0, 0, 0);
      }
      __syncthreads();
      pa = na; pb = nb;
    }
#undef VSTAGE

#pragma unroll
    for (int nt = 0; nt < 16; ++nt) {
      int nl = nt * 16 + lr;
      float bv2 = bv[n0 + nl];
#pragma unroll
      for (int r = 0; r < 4; ++r)
        lt[nl][w * 16 + lh * 4 + r] = f2bf(acc[nt][r] + bv2);
    }
    __syncthreads();
    const int bb = m0 >> 11;
    const int s0 = m0 & 2047;
    for (int i = tid; i < 256 * 64; i += 256) {
      int nn = i >> 6, mm = i & 63;
      int d = n0 + nn, t = s0 + mm;
      Vp[((size_t)(bb * 64 + (t >> 5)) * DD + d) * 32 + (t & 31)] = lt[nn][mm];
    }
  }
}

// ---- pass 1: S = QK^T in f16. Tile 128m x 256n, 8 waves of 64x64 (unchanged) ----
__global__ __launch_bounds__(512, 4)
void gemm_s(const ushort* __restrict__ Qp, const ushort* __restrict__ Kp,
            const float* __restrict__ isc, const u64* __restrict__ dbits,
            ushort* __restrict__ Pp, float* __restrict__ Z)
{
  const int bid = blockIdx.x;
  const int bb = bid & 7;
  const int tt = bid >> 3;
  const int m0 = (tt & 15) * 128;
  const int n0 = (tt >> 4) * 256;
  const int tid = threadIdx.x;
  const int w  = tid >> 6;
  const int l  = tid & 63;
  const int lr = l & 15;
  const int lh = l >> 4;
  const int wm = w & 1;
  const int wn = w >> 1;

  __shared__ __align__(16) char Qb[2][128][64];   // 16 KB
  __shared__ __align__(16) char Kb[2][256][64];   // 32 KB

  const int srow = (w << 4) + (l >> 2);
  const size_t gc = (size_t)srow * 64 + (size_t)((((l & 3) ^ ((srow >> 1) & 3))) << 4);

  const char* gq = (const char*)Qp + ((size_t)(bb * 7) * SS + m0) * 64;
  const char* gk = (const char*)Kp + ((size_t)(bb * 7) * SS + n0) * 64;

  const f32x4 fzero = {0.f, 0.f, 0.f, 0.f};
  f32x4 acc[4][4];
#pragma unroll
  for (int mf = 0; mf < 4; ++mf)
#pragma unroll
    for (int nf = 0; nf < 4; ++nf) acc[mf][nf] = fzero;

#define SSTAGE(buf, kk) do {                                            \
    size_t ko = (size_t)(kk) * (SS * 64);                               \
    gload16(gq + ko + gc,        &Qb[buf][w << 4][0]);                  \
    gload16(gk + ko + gc,        &Kb[buf][w << 4][0]);                  \
    gload16(gk + ko + gc + 8192, &Kb[buf][(w << 4) + 128][0]);          \
  } while (0)

  SSTAGE(0, 0);
  __syncthreads();
#pragma unroll 1
  for (int t = 0; t < 7; ++t) {
    const int buf = t & 1;
    if (t < 6) SSTAGE(buf ^ 1, t + 1);
    f16x8 bfr[4];
#pragma unroll
    for (int nf = 0; nf < 4; ++nf) {
      int br = wn * 64 + nf * 16 + lr;
      int bo = (lh ^ ((br >> 1) & 3)) << 4;
      bfr[nf] = *(const f16x8*)&Kb[buf][br][bo];
    }
#pragma unroll
    for (int mf = 0; mf < 4; ++mf) {
      int ar = wm * 64 + mf * 16 + lr;
      int ao = (lh ^ ((ar >> 1) & 3)) << 4;
      f16x8 af = *(const f16x8*)&Qb[buf][ar][ao];
#pragma unroll
      for (int nf = 0; nf < 4; ++nf)
        acc[mf][nf] = __builtin_amdgcn_mfma_f32_16x16x32_f16(af, bfr[nf], acc[mf][nf], 0, 0, 0);
    }
    __syncthreads();
  }
#undef SSTAGE

  // epilogue: sval = acc * rcp(isc), exp(.-MSHIFT), P~ = bit ? e/0.9 : 0
  const float KEEPR = 1.0f / 0.9f;
#pragma unroll
  for (int mf = 0; mf < 4; ++mf) {
#pragma unroll
    for (int r = 0; r < 4; ++r) {
      const int sr = m0 + wm * 64 + mf * 16 + lh * 4 + r;
      const u64 wbits = dbits[((size_t)bb * SS + sr) * 32 + (n0 >> 6) + (lr & 3)];
      float z = 0.f;
#pragma unroll
      for (int nf = 0; nf < 4; ++nf) {
        const int tc = n0 + wn * 64 + nf * 16 + lr;
        float iv = isc[(size_t)sr * SS + tc];
        float sval = acc[mf][nf][r] * __builtin_amdgcn_rcpf(iv);
        float e = __expf(sval - MSHIFT);
        z += e;
        float pm = ((wbits >> (wn * 16 + nf * 4 + (lr >> 2))) & 1ull) ? (e * KEEPR) : 0.f;
        Pp[((size_t)(bb * 64 + (tc >> 5)) * SS + sr) * 32 + (tc & 31)] = f2bf(pm);
      }
#pragma unroll
      for (int off = 1; off < 16; off <<= 1) z += __shfl_xor(z, off);
      if (lr == 0) atomicAdd(&Z[bb * SS + sr], z);
    }
  }
}

// ---- pass 2: O = (P~ V) / Z. 128x128, 4 waves of 64x64, m-adjacent tile order ----
__global__ __launch_bounds__(256, 4)
void gemm_pv(const ushort* __restrict__ Pp, const ushort* __restrict__ Vp,
             const float* __restrict__ Z, float* __restrict__ out)
{
  const int bid = blockIdx.x;
  const int bb = bid & 7;
  const int tt = bid >> 3;                // 0..95
  const int m_idx = tt / 6;
  const int n_idx = tt - m_idx * 6;
  const int m0 = m_idx * 128;
  const int n0 = n_idx * 128;
  const int tid = threadIdx.x;
  const int w  = tid >> 6;
  const int l  = tid & 63;
  const int lr = l & 15;
  const int lh = l >> 4;
  const int wm = w & 1;
  const int wn = w >> 1;

  __shared__ __align__(16) char Plb[2][128][64];
  __shared__ __align__(16) char Vlb[2][128][64];

  const int srow = (w << 4) + (l >> 2);
  const size_t gc = (size_t)srow * 64 + (size_t)((((l & 3) ^ ((srow >> 1) & 3))) << 4);

  const char* gpb = (const char*)Pp + ((size_t)(bb * 64) * SS + m0) * 64;
  const char* gvb = (const char*)Vp + ((size_t)(bb * 64) * DD + n0) * 64;

  const f32x4 fzero = {0.f, 0.f, 0.f, 0.f};
  f32x4 acc[4][4];
#pragma unroll
  for (int mf = 0; mf < 4; ++mf)
#pragma unroll
    for (int nf = 0; nf < 4; ++nf) acc[mf][nf] = fzero;

#define PVSTAGE(t) do {                                                   \
    size_t k0 = (size_t)(t) * 2;                                          \
    gload16(gpb + k0 * (SS * 64) + gc,              &Plb[0][w << 4][0]);  \
    gload16(gpb + k0 * (SS * 64) + gc + 4096,       &Plb[0][(w << 4) + 64][0]); \
    gload16(gpb + (k0 + 1) * (SS * 64) + gc,        &Plb[1][w << 4][0]);  \
    gload16(gpb + (k0 + 1) * (SS * 64) + gc + 4096, &Plb[1][(w << 4) + 64][0]); \
    gload16(gvb + k0 * (DD * 64) + gc,              &Vlb[0][w << 4][0]);  \
    gload16(gvb + k0 * (DD * 64) + gc + 4096,       &Vlb[0][(w << 4) + 64][0]); \
    gload16(gvb + (k0 + 1) * (DD * 64) + gc,        &Vlb[1][w << 4][0]);  \
    gload16(gvb + (k0 + 1) * (DD * 64) + gc + 4096, &Vlb[1][(w << 4) + 64][0]); \
  } while (0)

  PVSTAGE(0);
  __syncthreads();
#pragma unroll 1
  for (int t = 0; t < 32; ++t) {
#pragma unroll
    for (int pk = 0; pk < 2; ++pk) {
      bf16x8 bfr[4];
#pragma unroll
      for (int nf = 0; nf < 4; ++nf) {
        int br = wn * 64 + nf * 16 + lr;
        int bo = (lh ^ ((br >> 1) & 3)) << 4;
        bfr[nf] = *(const bf16x8*)&Vlb[pk][br][bo];
      }
#pragma unroll
      for (int mf = 0; mf < 4; ++mf) {
        int ar = wm * 64 + mf * 16 + lr;
        int ao = (lh ^ ((ar >> 1) & 3)) << 4;
        bf16x8 af = *(const bf16x8*)&Plb[pk][ar][ao];
#pragma unroll
        for (int nf = 0; nf < 4; ++nf)
          acc[mf][nf] = __builtin_amdgcn_mfma_f32_16x16x32_bf16(af, bfr[nf], acc[mf][nf], 0, 0, 0);
      }
    }
    __syncthreads();
    if (t < 31) {
      PVSTAGE(t + 1);
      __syncthreads();
    }
  }
#undef PVSTAGE

#pragma unroll
  for (int mf = 0; mf < 4; ++mf) {
#pragma unroll
    for (int r = 0; r < 4; ++r) {
      const int sr = m0 + wm * 64 + mf * 16 + lh * 4 + r;
      float rz = __builtin_amdgcn_rcpf(Z[bb * SS + sr]);
#pragma unroll
      for (int nf = 0; nf < 4; ++nf) {
        const int dc = n0 + wn * 64 + nf * 16 + lr;
        out[((size_t)bb * SS + sr) * DD + dc] = acc[mf][nf][r] * rz;
      }
    }
  }
}

extern "C" void kernel_launch(void* const* d_in, const int* in_sizes, int n_in,
                              void* d_out, int out_size, void* d_ws, size_t ws_size,
                              hipStream_t stream) {
  const float* x1  = (const float*)d_in[0];
  const float* x2  = (const float*)d_in[1];
  const float* x3  = (const float*)d_in[2];
  const float* Wq  = (const float*)d_in[3];
  const float* bq  = (const float*)d_in[4];
  const float* Wk  = (const float*)d_in[5];
  const float* bk  = (const float*)d_in[6];
  const float* Wv  = (const float*)d_in[7];
  const float* bv  = (const float*)d_in[8];
  const float* isc = (const float*)d_in[9];
  const float* dmk = (const float*)d_in[10];
  float* out = (float*)d_out;

  const size_t QKN = (size_t)NB * 7 * SS * 32;        // 3.67M (f16)
  const size_t VPN = (size_t)NB * 64 * DD * 32;       // 12.6M (bf16)
  const size_t WN  = (size_t)WROWS * DD;
  const size_t NV  = (size_t)DD * DD;
  const size_t PPN = (size_t)NB * 64 * SS * 32;       // 33.5M (bf16)

  ushort* Qp  = (ushort*)d_ws;
  ushort* Kp  = Qp + QKN;
  ushort* Vp  = Kp + QKN;
  ushort* Wqp = Vp + VPN;
  ushort* Wkp = Wqp + WN;
  ushort* Wvb = Wkp + WN;
  ushort* Pp  = Wvb + NV;
  float*  Zb  = (float*)(Pp + PPN);                   // [8][2048]
  u64*    dbits = (u64*)(Zb + NB * SS);               // [8][2048][32] u64

  dim3 blk(256);
  prep_w<<<dim3(512), blk, 0, stream>>>(Wq, Wk, Wv, Wqp, Wkp, Wvb, Zb);
  fused_proj<<<dim3(1792), blk, 0, stream>>>(x1, x2, x3, Wqp, Wkp, Wvb,
                                             bq, bk, bv, dmk, Qp, Kp, Vp, dbits);
  gemm_s <<<dim3(1024), dim3(512), 0, stream>>>(Qp, Kp, isc, dbits, Pp, Zb);
  gemm_pv<<<dim3(768),  dim3(256), 0, stream>>>(Pp, Vp, Zb, out);
}

// Round 20
// 242.834 us; speedup vs baseline: 1.0095x; 1.0095x over previous
//
#include <hip/hip_runtime.h>
#include <hip/hip_bf16.h>

typedef unsigned short ushort;
typedef unsigned long long u64;
typedef short bf16x8 __attribute__((ext_vector_type(8)));
typedef _Float16 f16x8 __attribute__((ext_vector_type(8)));
typedef float f32x4 __attribute__((ext_vector_type(4)));

#define NB 8
#define SS 2048
#define DD 768
#define DKV 214
#define DKP 224
#define WROWS 256
#define MSHIFT 40.0f

__device__ __forceinline__ float bf2f(ushort u) {
  union { unsigned int i; float f; } v; v.i = ((unsigned int)u) << 16; return v.f;
}
__device__ __forceinline__ ushort f2bf(float f) {
  union { float f; unsigned int i; } v; v.f = f;
  unsigned int x = v.i;
  return (ushort)((x + 0x7fffu + ((x >> 16) & 1u)) >> 16);
}
__device__ __forceinline__ ushort f2h(float f) {
  union { _Float16 h; ushort u; } cv; cv.h = (_Float16)f; return cv.u;
}
__device__ __forceinline__ bf16x8 cvt8v(f32x4 a, f32x4 b) {
  bf16x8 r;
#pragma unroll
  for (int j = 0; j < 4; ++j) { r[j] = (short)f2bf(a[j]); r[j + 4] = (short)f2bf(b[j]); }
  return r;
}
__device__ __forceinline__ f16x8 cvt8h(f32x4 a, f32x4 b) {
  f16x8 r;
#pragma unroll
  for (int j = 0; j < 4; ++j) { r[j] = (_Float16)a[j]; r[j + 4] = (_Float16)b[j]; }
  return r;
}
// async global->LDS, 16B per lane; LDS dest is wave-uniform base + lane*16
__device__ __forceinline__ void gload16(const void* g, void* l) {
  __builtin_amdgcn_global_load_lds(
      (const __attribute__((address_space(1))) void*)g,
      (__attribute__((address_space(3))) void*)l, 16, 0, 0);
}

// ---- fused prep: Z zero + weight packing + dmask bits (runs ALONE up front;
// the 7 TB/s dmask scan must not co-run with latency-sensitive projections).
__global__ __launch_bounds__(256)
void prep_all(const float* __restrict__ dmk, const float* __restrict__ Wq,
              const float* __restrict__ Wk, const float* __restrict__ Wv,
              u64* __restrict__ dbits, ushort* __restrict__ Wqp,
              ushort* __restrict__ Wkp, ushort* __restrict__ Wvb,
              float* __restrict__ Z)
{
  const int tid0 = blockIdx.x * 256 + threadIdx.x;
  const int stride = gridDim.x * 256;
  for (int i = tid0; i < NB * SS; i += stride) Z[i] = 0.f;
  const int NW = WROWS * DD;
  const int NV = DD * DD;
  for (int i = tid0; i < 2 * NW + NV; i += stride) {
    if (i < NW) {
      int r = i / DD, c = i % DD;
      float v = (r < DKV) ? Wq[i] : 0.f;
      Wqp[(c >> 5) * (WROWS * 32) + r * 32 + (c & 31)] = f2h(v);
    } else if (i < 2 * NW) {
      int j = i - NW;
      int r = j / DD, c = j % DD;
      float v = (r < DKV) ? Wk[j] : 0.f;
      Wkp[(c >> 5) * (WROWS * 32) + r * 32 + (c & 31)] = f2h(v);
    } else {
      int j = i - 2 * NW;
      int r = j / DD, c = j % DD;
      Wvb[(c >> 5) * (DD * 32) + r * 32 + (c & 31)] = f2bf(Wv[j]);
    }
  }
  // dmask scan (ballot-native: word q of 256-chunk holds bit l = elem 4l+q)
  const int l = threadIdx.x & 63;
  const int wv = tid0 >> 6;
  const int nw = stride >> 6;
  const size_t nchunks = (size_t)NB * SS * SS / 256;
  for (size_t c = wv; c < nchunks; c += nw) {
    f32x4 v = *(const f32x4*)(dmk + c * 256 + 4 * l);
    u64 b0 = __ballot(v[0] > 0.5f);
    u64 b1 = __ballot(v[1] > 0.5f);
    u64 b2 = __ballot(v[2] > 0.5f);
    u64 b3 = __ballot(v[3] > 0.5f);
    if (l == 0) {
      u64* d = dbits + c * 4;
      d[0] = b0; d[1] = b1; d[2] = b2; d[3] = b3;
    }
  }
}

// ---- proj_qv: blocks [0,768) = V projection; [768,1280) = Q/K projection.
// Homogeneous compute bodies only (no BW-hog scan). Bodies verbatim from R18/R19.
__global__ __launch_bounds__(256, 3)
void proj_qv(const float* __restrict__ x1, const float* __restrict__ x2,
             const float* __restrict__ x3,
             const ushort* __restrict__ Wqp, const ushort* __restrict__ Wkp,
             const ushort* __restrict__ Wvb,
             const float* __restrict__ bq, const float* __restrict__ bk,
             const float* __restrict__ bv,
             ushort* __restrict__ Qp, ushort* __restrict__ Kp,
             ushort* __restrict__ Vp)
{
  __shared__ __align__(16) char smem[36864];
  const int bid = blockIdx.x;
  const int tid = threadIdx.x;
  const int w  = tid >> 6;
  const int l  = tid & 63;
  const int lr = l & 15;
  const int lh = l >> 4;

  const int srow = (w << 4) + (l >> 2);
  const size_t gc = (size_t)srow * 64 + (size_t)((((l & 3) ^ ((srow >> 1) & 3))) << 4);
  const f32x4 fzero = {0.f, 0.f, 0.f, 0.f};

  if (bid >= 768) {
    // ---- Q/K projection: 64m x 224n, wave = 16m x 224n, acc[14], dbuf slab ----
    const int b2 = bid - 768;
    const int m0 = (b2 & 255) * 64;
    const int which = b2 >> 8;
    const float*  A    = which ? x2 : x1;
    const ushort* Bw   = which ? Wkp : Wqp;
    const float*  bias = which ? bk : bq;
    ushort* Cp = which ? Kp : Qp;

    typedef char QBuf[256][64];
    QBuf* lds = (QBuf*)smem;                    // lds[2][256][64] = 32 KB
    const char* gb = (const char*)Bw;

    f32x4 acc[14];
#pragma unroll
    for (int nt = 0; nt < 14; ++nt) acc[nt] = fzero;

    const float* arow = A + (size_t)(m0 + w * 16 + lr) * DD + lh * 8;

#define QKSTAGE(buf, kk) do {                                             \
    size_t ko = (size_t)(kk) * (WROWS * 64);                              \
    gload16(gb + ko + gc,         &lds[buf][w << 4][0]);                  \
    gload16(gb + ko + gc + 4096,  &lds[buf][(w << 4) + 64][0]);           \
    gload16(gb + ko + gc + 8192,  &lds[buf][(w << 4) + 128][0]);          \
    gload16(gb + ko + gc + 12288, &lds[buf][(w << 4) + 192][0]);          \
  } while (0)

    QKSTAGE(0, 0);
    f32x4 pa = *(const f32x4*)(arow);
    f32x4 pb = *(const f32x4*)(arow + 4);
    __syncthreads();

    for (int kk = 0; kk < 24; ++kk) {
      const int buf = kk & 1;
      if (kk < 23) QKSTAGE(buf ^ 1, kk + 1);
      f32x4 na = fzero, nb = fzero;
      if (kk < 23) {
        na = *(const f32x4*)(arow + (kk + 1) * 32);
        nb = *(const f32x4*)(arow + (kk + 1) * 32 + 4);
      }
      f16x8 af = cvt8h(pa, pb);
#pragma unroll
      for (int nt = 0; nt < 14; ++nt) {
        int br = nt * 16 + lr;
        int bo = (lh ^ ((br >> 1) & 3)) << 4;
        f16x8 wf = *(const f16x8*)&lds[buf][br][bo];
        acc[nt] = __builtin_amdgcn_mfma_f32_16x16x32_f16(af, wf, acc[nt], 0, 0, 0);
      }
      __syncthreads();
      pa = na; pb = nb;
    }
#undef QKSTAGE

#pragma unroll
    for (int nt = 0; nt < 14; ++nt) {
      int n = nt * 16 + lr;                   // < 224 by construction
      float bv2 = (n < DKV) ? bias[n] : 0.f;
#pragma unroll
      for (int r = 0; r < 4; ++r) {
        int m = m0 + w * 16 + lh * 4 + r;
        int bb = m >> 11, s = m & 2047;
        float val = (n < DKV) ? (acc[nt][r] + bv2) : 0.f;
        Cp[((size_t)(bb * 7 + (n >> 5)) * SS + s) * 32 + (n & 31)] = f2h(val);
      }
    }
    return;
  }

  // ---- V projection: 64m x 256n, wave = 16m x 256n, acc[16], dbuf + lt union ----
  {
    const int m0 = (bid & 255) * 64;
    const int n0 = (bid >> 8) * 256;

    typedef char VBuf[256][64];
    VBuf* stage = (VBuf*)smem;
    ushort (*lt)[72] = (ushort(*)[72])smem;

    const char* gvw = (const char*)Wvb + (size_t)n0 * 64;

    f32x4 acc[16];
#pragma unroll
    for (int nt = 0; nt < 16; ++nt) acc[nt] = fzero;

    const float* arow = x3 + (size_t)(m0 + w * 16 + lr) * DD + lh * 8;

#define VSTAGE(buf, kk) do {                                              \
    size_t ko = (size_t)(kk) * (DD * 64);                                 \
    gload16(gvw + ko + gc,         &stage[buf][w << 4][0]);               \
    gload16(gvw + ko + gc + 4096,  &stage[buf][(w << 4) + 64][0]);        \
    gload16(gvw + ko + gc + 8192,  &stage[buf][(w << 4) + 128][0]);       \
    gload16(gvw + ko + gc + 12288, &stage[buf][(w << 4) + 192][0]);       \
  } while (0)

    VSTAGE(0, 0);
    f32x4 pa = *(const f32x4*)(arow);
    f32x4 pb = *(const f32x4*)(arow + 4);
    __syncthreads();

    for (int kk = 0; kk < 24; ++kk) {
      const int buf = kk & 1;
      if (kk < 23) VSTAGE(buf ^ 1, kk + 1);
      f32x4 na = fzero, nb = fzero;
      if (kk < 23) {
        na = *(const f32x4*)(arow + (kk + 1) * 32);
        nb = *(const f32x4*)(arow + (kk + 1) * 32 + 4);
      }
      bf16x8 af = cvt8v(pa, pb);
#pragma unroll
      for (int nt = 0; nt < 16; ++nt) {
        int br = nt * 16 + lr;
        int bo = (lh ^ ((br >> 1) & 3)) << 4;
        bf16x8 bfr = *(const bf16x8*)&stage[buf][br][bo];
        acc[nt] = __builtin_amdgcn_mfma_f32_16x16x32_bf16(af, bfr, acc[nt], 0, 0, 0);
      }
      __syncthreads();
      pa = na; pb = nb;
    }
#undef VSTAGE

#pragma unroll
    for (int nt = 0; nt < 16; ++nt) {
      int nl = nt * 16 + lr;
      float bv2 = bv[n0 + nl];
#pragma unroll
      for (int r = 0; r < 4; ++r)
        lt[nl][w * 16 + lh * 4 + r] = f2bf(acc[nt][r] + bv2);
    }
    __syncthreads();
    const int bb = m0 >> 11;
    const int s0 = m0 & 2047;
    for (int i = tid; i < 256 * 64; i += 256) {
      int nn = i >> 6, mm = i & 63;
      int d = n0 + nn, t = s0 + mm;
      Vp[((size_t)(bb * 64 + (t >> 5)) * DD + d) * 32 + (t & 31)] = lt[nn][mm];
    }
  }
}

// ---- pass 1: S = QK^T in f16. Tile 128m x 256n, 8 waves of 64x64 (unchanged) ----
__global__ __launch_bounds__(512, 4)
void gemm_s(const ushort* __restrict__ Qp, const ushort* __restrict__ Kp,
            const float* __restrict__ isc, const u64* __restrict__ dbits,
            ushort* __restrict__ Pp, float* __restrict__ Z)
{
  const int bid = blockIdx.x;
  const int bb = bid & 7;
  const int tt = bid >> 3;
  const int m0 = (tt & 15) * 128;
  const int n0 = (tt >> 4) * 256;
  const int tid = threadIdx.x;
  const int w  = tid >> 6;
  const int l  = tid & 63;
  const int lr = l & 15;
  const int lh = l >> 4;
  const int wm = w & 1;
  const int wn = w >> 1;

  __shared__ __align__(16) char Qb[2][128][64];   // 16 KB
  __shared__ __align__(16) char Kb[2][256][64];   // 32 KB

  const int srow = (w << 4) + (l >> 2);
  const size_t gc = (size_t)srow * 64 + (size_t)((((l & 3) ^ ((srow >> 1) & 3))) << 4);

  const char* gq = (const char*)Qp + ((size_t)(bb * 7) * SS + m0) * 64;
  const char* gk = (const char*)Kp + ((size_t)(bb * 7) * SS + n0) * 64;

  const f32x4 fzero = {0.f, 0.f, 0.f, 0.f};
  f32x4 acc[4][4];
#pragma unroll
  for (int mf = 0; mf < 4; ++mf)
#pragma unroll
    for (int nf = 0; nf < 4; ++nf) acc[mf][nf] = fzero;

#define SSTAGE(buf, kk) do {                                            \
    size_t ko = (size_t)(kk) * (SS * 64);                               \
    gload16(gq + ko + gc,        &Qb[buf][w << 4][0]);                  \
    gload16(gk + ko + gc,        &Kb[buf][w << 4][0]);                  \
    gload16(gk + ko + gc + 8192, &Kb[buf][(w << 4) + 128][0]);          \
  } while (0)

  SSTAGE(0, 0);
  __syncthreads();
#pragma unroll 1
  for (int t = 0; t < 7; ++t) {
    const int buf = t & 1;
    if (t < 6) SSTAGE(buf ^ 1, t + 1);
    f16x8 bfr[4];
#pragma unroll
    for (int nf = 0; nf < 4; ++nf) {
      int br = wn * 64 + nf * 16 + lr;
      int bo = (lh ^ ((br >> 1) & 3)) << 4;
      bfr[nf] = *(const f16x8*)&Kb[buf][br][bo];
    }
#pragma unroll
    for (int mf = 0; mf < 4; ++mf) {
      int ar = wm * 64 + mf * 16 + lr;
      int ao = (lh ^ ((ar >> 1) & 3)) << 4;
      f16x8 af = *(const f16x8*)&Qb[buf][ar][ao];
#pragma unroll
      for (int nf = 0; nf < 4; ++nf)
        acc[mf][nf] = __builtin_amdgcn_mfma_f32_16x16x32_f16(af, bfr[nf], acc[mf][nf], 0, 0, 0);
    }
    __syncthreads();
  }
#undef SSTAGE

  // epilogue: sval = acc * rcp(isc), exp(.-MSHIFT), P~ = bit ? e/0.9 : 0
  const float KEEPR = 1.0f / 0.9f;
#pragma unroll
  for (int mf = 0; mf < 4; ++mf) {
#pragma unroll
    for (int r = 0; r < 4; ++r) {
      const int sr = m0 + wm * 64 + mf * 16 + lh * 4 + r;
      const u64 wbits = dbits[((size_t)bb * SS + sr) * 32 + (n0 >> 6) + (lr & 3)];
      float z = 0.f;
#pragma unroll
      for (int nf = 0; nf < 4; ++nf) {
        const int tc = n0 + wn * 64 + nf * 16 + lr;
        float iv = isc[(size_t)sr * SS + tc];
        float sval = acc[mf][nf][r] * __builtin_amdgcn_rcpf(iv);
        float e = __expf(sval - MSHIFT);
        z += e;
        float pm = ((wbits >> (wn * 16 + nf * 4 + (lr >> 2))) & 1ull) ? (e * KEEPR) : 0.f;
        Pp[((size_t)(bb * 64 + (tc >> 5)) * SS + sr) * 32 + (tc & 31)] = f2bf(pm);
      }
#pragma unroll
      for (int off = 1; off < 16; off <<= 1) z += __shfl_xor(z, off);
      if (lr == 0) atomicAdd(&Z[bb * SS + sr], z);
    }
  }
}

// ---- pass 2: O = (P~ V) / Z. 128x128, 4 waves of 64x64, m-adjacent tile order ----
__global__ __launch_bounds__(256, 4)
void gemm_pv(const ushort* __restrict__ Pp, const ushort* __restrict__ Vp,
             const float* __restrict__ Z, float* __restrict__ out)
{
  const int bid = blockIdx.x;
  const int bb = bid & 7;
  const int tt = bid >> 3;                // 0..95
  const int m_idx = tt / 6;
  const int n_idx = tt - m_idx * 6;
  const int m0 = m_idx * 128;
  const int n0 = n_idx * 128;
  const int tid = threadIdx.x;
  const int w  = tid >> 6;
  const int l  = tid & 63;
  const int lr = l & 15;
  const int lh = l >> 4;
  const int wm = w & 1;
  const int wn = w >> 1;

  __shared__ __align__(16) char Plb[2][128][64];
  __shared__ __align__(16) char Vlb[2][128][64];

  const int srow = (w << 4) + (l >> 2);
  const size_t gc = (size_t)srow * 64 + (size_t)((((l & 3) ^ ((srow >> 1) & 3))) << 4);

  const char* gpb = (const char*)Pp + ((size_t)(bb * 64) * SS + m0) * 64;
  const char* gvb = (const char*)Vp + ((size_t)(bb * 64) * DD + n0) * 64;

  const f32x4 fzero = {0.f, 0.f, 0.f, 0.f};
  f32x4 acc[4][4];
#pragma unroll
  for (int mf = 0; mf < 4; ++mf)
#pragma unroll
    for (int nf = 0; nf < 4; ++nf) acc[mf][nf] = fzero;

#define PVSTAGE(t) do {                                                   \
    size_t k0 = (size_t)(t) * 2;                                          \
    gload16(gpb + k0 * (SS * 64) + gc,              &Plb[0][w << 4][0]);  \
    gload16(gpb + k0 * (SS * 64) + gc + 4096,       &Plb[0][(w << 4) + 64][0]); \
    gload16(gpb + (k0 + 1) * (SS * 64) + gc,        &Plb[1][w << 4][0]);  \
    gload16(gpb + (k0 + 1) * (SS * 64) + gc + 4096, &Plb[1][(w << 4) + 64][0]); \
    gload16(gvb + k0 * (DD * 64) + gc,              &Vlb[0][w << 4][0]);  \
    gload16(gvb + k0 * (DD * 64) + gc + 4096,       &Vlb[0][(w << 4) + 64][0]); \
    gload16(gvb + (k0 + 1) * (DD * 64) + gc,        &Vlb[1][w << 4][0]);  \
    gload16(gvb + (k0 + 1) * (DD * 64) + gc + 4096, &Vlb[1][(w << 4) + 64][0]); \
  } while (0)

  PVSTAGE(0);
  __syncthreads();
#pragma unroll 1
  for (int t = 0; t < 32; ++t) {
#pragma unroll
    for (int pk = 0; pk < 2; ++pk) {
      bf16x8 bfr[4];
#pragma unroll
      for (int nf = 0; nf < 4; ++nf) {
        int br = wn * 64 + nf * 16 + lr;
        int bo = (lh ^ ((br >> 1) & 3)) << 4;
        bfr[nf] = *(const bf16x8*)&Vlb[pk][br][bo];
      }
#pragma unroll
      for (int mf = 0; mf < 4; ++mf) {
        int ar = wm * 64 + mf * 16 + lr;
        int ao = (lh ^ ((ar >> 1) & 3)) << 4;
        bf16x8 af = *(const bf16x8*)&Plb[pk][ar][ao];
#pragma unroll
        for (int nf = 0; nf < 4; ++nf)
          acc[mf][nf] = __builtin_amdgcn_mfma_f32_16x16x32_bf16(af, bfr[nf], acc[mf][nf], 0, 0, 0);
      }
    }
    __syncthreads();
    if (t < 31) {
      PVSTAGE(t + 1);
      __syncthreads();
    }
  }
#undef PVSTAGE

#pragma unroll
  for (int mf = 0; mf < 4; ++mf) {
#pragma unroll
    for (int r = 0; r < 4; ++r) {
      const int sr = m0 + wm * 64 + mf * 16 + lh * 4 + r;
      float rz = __builtin_amdgcn_rcpf(Z[bb * SS + sr]);
#pragma unroll
      for (int nf = 0; nf < 4; ++nf) {
        const int dc = n0 + wn * 64 + nf * 16 + lr;
        out[((size_t)bb * SS + sr) * DD + dc] = acc[mf][nf][r] * rz;
      }
    }
  }
}

extern "C" void kernel_launch(void* const* d_in, const int* in_sizes, int n_in,
                              void* d_out, int out_size, void* d_ws, size_t ws_size,
                              hipStream_t stream) {
  const float* x1  = (const float*)d_in[0];
  const float* x2  = (const float*)d_in[1];
  const float* x3  = (const float*)d_in[2];
  const float* Wq  = (const float*)d_in[3];
  const float* bq  = (const float*)d_in[4];
  const float* Wk  = (const float*)d_in[5];
  const float* bk  = (const float*)d_in[6];
  const float* Wv  = (const float*)d_in[7];
  const float* bv  = (const float*)d_in[8];
  const float* isc = (const float*)d_in[9];
  const float* dmk = (const float*)d_in[10];
  float* out = (float*)d_out;

  const size_t QKN = (size_t)NB * 7 * SS * 32;        // 3.67M (f16)
  const size_t VPN = (size_t)NB * 64 * DD * 32;       // 12.6M (bf16)
  const size_t WN  = (size_t)WROWS * DD;
  const size_t NV  = (size_t)DD * DD;
  const size_t PPN = (size_t)NB * 64 * SS * 32;       // 33.5M (bf16)

  ushort* Qp  = (ushort*)d_ws;
  ushort* Kp  = Qp + QKN;
  ushort* Vp  = Kp + QKN;
  ushort* Wqp = Vp + VPN;
  ushort* Wkp = Wqp + WN;
  ushort* Wvb = Wkp + WN;
  ushort* Pp  = Wvb + NV;
  float*  Zb  = (float*)(Pp + PPN);                   // [8][2048]
  u64*    dbits = (u64*)(Zb + NB * SS);               // [8][2048][32] u64

  dim3 blk(256);
  prep_all<<<dim3(2048), blk, 0, stream>>>(dmk, Wq, Wk, Wv, dbits, Wqp, Wkp, Wvb, Zb);
  proj_qv<<<dim3(1280), blk, 0, stream>>>(x1, x2, x3, Wqp, Wkp, Wvb,
                                          bq, bk, bv, Qp, Kp, Vp);
  gemm_s <<<dim3(1024), dim3(512), 0, stream>>>(Qp, Kp, isc, dbits, Pp, Zb);
  gemm_pv<<<dim3(768),  dim3(256), 0, stream>>>(Pp, Vp, Zb, out);
}

// Round 21
// 237.120 us; speedup vs baseline: 1.0338x; 1.0241x over previous
//
#include <hip/hip_runtime.h>
#include <hip/hip_bf16.h>

typedef unsigned short ushort;
typedef unsigned long long u64;
typedef short bf16x8 __attribute__((ext_vector_type(8)));
typedef _Float16 f16x8 __attribute__((ext_vector_type(8)));
typedef float f32x4 __attribute__((ext_vector_type(4)));

#define NB 8
#define SS 2048
#define DD 768
#define DKV 214
#define DKP 224
#define WROWS 256
#define MSHIFT 40.0f

__device__ __forceinline__ float bf2f(ushort u) {
  union { unsigned int i; float f; } v; v.i = ((unsigned int)u) << 16; return v.f;
}
__device__ __forceinline__ ushort f2bf(float f) {
  union { float f; unsigned int i; } v; v.f = f;
  unsigned int x = v.i;
  return (ushort)((x + 0x7fffu + ((x >> 16) & 1u)) >> 16);
}
__device__ __forceinline__ ushort f2h(float f) {
  union { _Float16 h; ushort u; } cv; cv.h = (_Float16)f; return cv.u;
}
__device__ __forceinline__ bf16x8 cvt8v(f32x4 a, f32x4 b) {
  bf16x8 r;
#pragma unroll
  for (int j = 0; j < 4; ++j) { r[j] = (short)f2bf(a[j]); r[j + 4] = (short)f2bf(b[j]); }
  return r;
}
__device__ __forceinline__ f16x8 cvt8h(f32x4 a, f32x4 b) {
  f16x8 r;
#pragma unroll
  for (int j = 0; j < 4; ++j) { r[j] = (_Float16)a[j]; r[j + 4] = (_Float16)b[j]; }
  return r;
}
// async global->LDS, 16B per lane; LDS dest is wave-uniform base + lane*16
__device__ __forceinline__ void gload16(const void* g, void* l) {
  __builtin_amdgcn_global_load_lds(
      (const __attribute__((address_space(1))) void*)g,
      (__attribute__((address_space(3))) void*)l, 16, 0, 0);
}

// ---- fused prep: Z zero + weight packing + dmask bits (ballot-native layout).
// Runs alone up front (BW-hog scan must not co-run with latency-sensitive GEMMs).
__global__ __launch_bounds__(256)
void prep_all(const float* __restrict__ dmk, const float* __restrict__ Wq,
              const float* __restrict__ Wk, const float* __restrict__ Wv,
              u64* __restrict__ dbits, ushort* __restrict__ Wqp,
              ushort* __restrict__ Wkp, ushort* __restrict__ Wvb,
              float* __restrict__ Z)
{
  const int tid0 = blockIdx.x * 256 + threadIdx.x;
  const int stride = gridDim.x * 256;
  for (int i = tid0; i < NB * SS; i += stride) Z[i] = 0.f;
  const int NW = WROWS * DD;
  const int NV = DD * DD;
  for (int i = tid0; i < 2 * NW + NV; i += stride) {
    if (i < NW) {
      int r = i / DD, c = i % DD;
      float v = (r < DKV) ? Wq[i] : 0.f;
      Wqp[(c >> 5) * (WROWS * 32) + r * 32 + (c & 31)] = f2h(v);
    } else if (i < 2 * NW) {
      int j = i - NW;
      int r = j / DD, c = j % DD;
      float v = (r < DKV) ? Wk[j] : 0.f;
      Wkp[(c >> 5) * (WROWS * 32) + r * 32 + (c & 31)] = f2h(v);
    } else {
      int j = i - 2 * NW;
      int r = j / DD, c = j % DD;
      Wvb[(c >> 5) * (DD * 32) + r * 32 + (c & 31)] = f2bf(Wv[j]);
    }
  }
  // dmask scan (ballot-native: word q of 256-chunk holds bit l = elem 4l+q)
  const int l = threadIdx.x & 63;
  const int wv = tid0 >> 6;
  const int nw = stride >> 6;
  const size_t nchunks = (size_t)NB * SS * SS / 256;
  for (size_t c = wv; c < nchunks; c += nw) {
    f32x4 v = *(const f32x4*)(dmk + c * 256 + 4 * l);
    u64 b0 = __ballot(v[0] > 0.5f);
    u64 b1 = __ballot(v[1] > 0.5f);
    u64 b2 = __ballot(v[2] > 0.5f);
    u64 b3 = __ballot(v[3] > 0.5f);
    if (l == 0) {
      u64* d = dbits + c * 4;
      d[0] = b0; d[1] = b1; d[2] = b2; d[3] = b3;
    }
  }
}

// ---- fused Q+K projection (f16, single MFMA). Block = 64m x 224n (full n:
// each x row read ONCE). Wave = 16m x 224n, acc[14]. Grid (256, 2),
// dbuf-staged B slab (padded 256 rows, nt<14 so pad never consumed).
__global__ __launch_bounds__(256, 4)
void gemm_qk(const float* __restrict__ x1, const float* __restrict__ x2,
             const ushort* __restrict__ Wqp, const ushort* __restrict__ Wkp,
             const float* __restrict__ bq, const float* __restrict__ bk,
             ushort* __restrict__ Qp, ushort* __restrict__ Kp)
{
  const int m0 = blockIdx.x * 64;
  const int which = blockIdx.y;
  const int tid = threadIdx.x;
  const int w  = tid >> 6;
  const int l  = tid & 63;
  const int lr = l & 15;
  const int lh = l >> 4;

  const float*  A    = which ? x2 : x1;
  const ushort* Bw   = which ? Wkp : Wqp;
  const float*  bias = which ? bk : bq;
  ushort* Cp = which ? Kp : Qp;

  __shared__ __align__(16) char lds[2][256][64];      // 32 KB

  const int srow = (w << 4) + (l >> 2);
  const size_t gc = (size_t)srow * 64 + (size_t)((((l & 3) ^ ((srow >> 1) & 3))) << 4);
  const char* gb = (const char*)Bw;

  const f32x4 fzero = {0.f, 0.f, 0.f, 0.f};
  f32x4 acc[14];
#pragma unroll
  for (int nt = 0; nt < 14; ++nt) acc[nt] = fzero;

  const float* arow = A + (size_t)(m0 + w * 16 + lr) * DD + lh * 8;

#define QKSTAGE(buf, kk) do {                                             \
    size_t ko = (size_t)(kk) * (WROWS * 64);                              \
    gload16(gb + ko + gc,         &lds[buf][w << 4][0]);                  \
    gload16(gb + ko + gc + 4096,  &lds[buf][(w << 4) + 64][0]);           \
    gload16(gb + ko + gc + 8192,  &lds[buf][(w << 4) + 128][0]);          \
    gload16(gb + ko + gc + 12288, &lds[buf][(w << 4) + 192][0]);          \
  } while (0)

  QKSTAGE(0, 0);
  f32x4 pa = *(const f32x4*)(arow);
  f32x4 pb = *(const f32x4*)(arow + 4);
  __syncthreads();

  for (int kk = 0; kk < 24; ++kk) {
    const int buf = kk & 1;
    if (kk < 23) QKSTAGE(buf ^ 1, kk + 1);
    f32x4 na = fzero, nb = fzero;
    if (kk < 23) {
      na = *(const f32x4*)(arow + (kk + 1) * 32);
      nb = *(const f32x4*)(arow + (kk + 1) * 32 + 4);
    }
    f16x8 af = cvt8h(pa, pb);
#pragma unroll
    for (int nt = 0; nt < 14; ++nt) {
      int br = nt * 16 + lr;
      int bo = (lh ^ ((br >> 1) & 3)) << 4;
      f16x8 wf = *(const f16x8*)&lds[buf][br][bo];
      acc[nt] = __builtin_amdgcn_mfma_f32_16x16x32_f16(af, wf, acc[nt], 0, 0, 0);
    }
    __syncthreads();
    pa = na; pb = nb;
  }
#undef QKSTAGE

#pragma unroll
  for (int nt = 0; nt < 14; ++nt) {
    int n = nt * 16 + lr;                   // < 224 by construction
    float bv = (n < DKV) ? bias[n] : 0.f;
#pragma unroll
    for (int r = 0; r < 4; ++r) {
      int m = m0 + w * 16 + lh * 4 + r;
      int bb = m >> 11, s = m & 2047;
      float val = (n < DKV) ? (acc[nt][r] + bv) : 0.f;
      Cp[((size_t)(bb * 7 + (n >> 5)) * SS + s) * 32 + (n & 31)] = f2h(val);
    }
  }
}

// ---- V projection -> k-packed Vp[b][64][768][32] bf16 (wave = 16m x 256n) ----
__global__ __launch_bounds__(256, 3)
void gemm_v(const float* __restrict__ A, const ushort* __restrict__ Bw,
            const float* __restrict__ bias, ushort* __restrict__ Vp)
{
  const int m0 = blockIdx.x * 64;
  const int n0 = blockIdx.y * 256;
  const int tid = threadIdx.x;
  const int w  = tid >> 6;
  const int l  = tid & 63;
  const int lr = l & 15;
  const int lh = l >> 4;

  __shared__ __align__(16) char smem[36864];
  typedef char VBuf[256][64];
  VBuf* stage = (VBuf*)smem;
  ushort (*lt)[72] = (ushort(*)[72])smem;

  const int srow = (w << 4) + (l >> 2);
  const size_t gc = (size_t)srow * 64 + (size_t)((((l & 3) ^ ((srow >> 1) & 3))) << 4);
  const char* gvw = (const char*)Bw + (size_t)n0 * 64;

  const f32x4 fzero = {0.f, 0.f, 0.f, 0.f};
  f32x4 acc[16];
#pragma unroll
  for (int nt = 0; nt < 16; ++nt) acc[nt] = fzero;

  const float* arow = A + (size_t)(m0 + w * 16 + lr) * DD + lh * 8;

#define VSTAGE(buf, kk) do {                                              \
    size_t ko = (size_t)(kk) * (DD * 64);                                 \
    gload16(gvw + ko + gc,         &stage[buf][w << 4][0]);               \
    gload16(gvw + ko + gc + 4096,  &stage[buf][(w << 4) + 64][0]);        \
    gload16(gvw + ko + gc + 8192,  &stage[buf][(w << 4) + 128][0]);       \
    gload16(gvw + ko + gc + 12288, &stage[buf][(w << 4) + 192][0]);       \
  } while (0)

  VSTAGE(0, 0);
  f32x4 pa = *(const f32x4*)(arow);
  f32x4 pb = *(const f32x4*)(arow + 4);
  __syncthreads();

  for (int kk = 0; kk < 24; ++kk) {
    const int buf = kk & 1;
    if (kk < 23) VSTAGE(buf ^ 1, kk + 1);
    f32x4 na = fzero, nb = fzero;
    if (kk < 23) {
      na = *(const f32x4*)(arow + (kk + 1) * 32);
      nb = *(const f32x4*)(arow + (kk + 1) * 32 + 4);
    }
    bf16x8 af = cvt8v(pa, pb);
#pragma unroll
    for (int nt = 0; nt < 16; ++nt) {
      int br = nt * 16 + lr;
      int bo = (lh ^ ((br >> 1) & 3)) << 4;
      bf16x8 bfr = *(const bf16x8*)&stage[buf][br][bo];
      acc[nt] = __builtin_amdgcn_mfma_f32_16x16x32_bf16(af, bfr, acc[nt], 0, 0, 0);
    }
    __syncthreads();
    pa = na; pb = nb;
  }
#undef VSTAGE

#pragma unroll
  for (int nt = 0; nt < 16; ++nt) {
    int nl = nt * 16 + lr;
    float bv = bias[n0 + nl];
#pragma unroll
    for (int r = 0; r < 4; ++r)
      lt[nl][w * 16 + lh * 4 + r] = f2bf(acc[nt][r] + bv);
  }
  __syncthreads();
  const int bb = m0 >> 11;
  const int s0 = m0 & 2047;
  for (int i = tid; i < 256 * 64; i += 256) {
    int nn = i >> 6, mm = i & 63;
    int d = n0 + nn, t = s0 + mm;
    Vp[((size_t)(bb * 64 + (t >> 5)) * DD + d) * 32 + (t & 31)] = lt[nn][mm];
  }
}

// ---- pass 1: S = QK^T in f16. Tile 128m x 256n, 8 waves of 64x64.
// dbits: word = row*32 + (n0>>6) + (lr&3), bit = wn*16 + nf*4 + (lr>>2).
__global__ __launch_bounds__(512, 4)
void gemm_s(const ushort* __restrict__ Qp, const ushort* __restrict__ Kp,
            const float* __restrict__ isc, const u64* __restrict__ dbits,
            ushort* __restrict__ Pp, float* __restrict__ Z)
{
  const int bid = blockIdx.x;
  const int bb = bid & 7;
  const int tt = bid >> 3;
  const int m0 = (tt & 15) * 128;
  const int n0 = (tt >> 4) * 256;
  const int tid = threadIdx.x;
  const int w  = tid >> 6;
  const int l  = tid & 63;
  const int lr = l & 15;
  const int lh = l >> 4;
  const int wm = w & 1;
  const int wn = w >> 1;

  __shared__ __align__(16) char Qb[2][128][64];   // 16 KB
  __shared__ __align__(16) char Kb[2][256][64];   // 32 KB

  const int srow = (w << 4) + (l >> 2);
  const size_t gc = (size_t)srow * 64 + (size_t)((((l & 3) ^ ((srow >> 1) & 3))) << 4);

  const char* gq = (const char*)Qp + ((size_t)(bb * 7) * SS + m0) * 64;
  const char* gk = (const char*)Kp + ((size_t)(bb * 7) * SS + n0) * 64;

  const f32x4 fzero = {0.f, 0.f, 0.f, 0.f};
  f32x4 acc[4][4];
#pragma unroll
  for (int mf = 0; mf < 4; ++mf)
#pragma unroll
    for (int nf = 0; nf < 4; ++nf) acc[mf][nf] = fzero;

#define SSTAGE(buf, kk) do {                                            \
    size_t ko = (size_t)(kk) * (SS * 64);                               \
    gload16(gq + ko + gc,        &Qb[buf][w << 4][0]);                  \
    gload16(gk + ko + gc,        &Kb[buf][w << 4][0]);                  \
    gload16(gk + ko + gc + 8192, &Kb[buf][(w << 4) + 128][0]);          \
  } while (0)

  SSTAGE(0, 0);
  __syncthreads();
#pragma unroll 1
  for (int t = 0; t < 7; ++t) {
    const int buf = t & 1;
    if (t < 6) SSTAGE(buf ^ 1, t + 1);
    f16x8 bfr[4];
#pragma unroll
    for (int nf = 0; nf < 4; ++nf) {
      int br = wn * 64 + nf * 16 + lr;
      int bo = (lh ^ ((br >> 1) & 3)) << 4;
      bfr[nf] = *(const f16x8*)&Kb[buf][br][bo];
    }
#pragma unroll
    for (int mf = 0; mf < 4; ++mf) {
      int ar = wm * 64 + mf * 16 + lr;
      int ao = (lh ^ ((ar >> 1) & 3)) << 4;
      f16x8 af = *(const f16x8*)&Qb[buf][ar][ao];
#pragma unroll
      for (int nf = 0; nf < 4; ++nf)
        acc[mf][nf] = __builtin_amdgcn_mfma_f32_16x16x32_f16(af, bfr[nf], acc[mf][nf], 0, 0, 0);
    }
    __syncthreads();
  }
#undef SSTAGE

  // epilogue: sval = acc * rcp(isc), exp(.-MSHIFT), P~ = bit ? e/0.9 : 0
  const float KEEPR = 1.0f / 0.9f;
#pragma unroll
  for (int mf = 0; mf < 4; ++mf) {
#pragma unroll
    for (int r = 0; r < 4; ++r) {
      const int sr = m0 + wm * 64 + mf * 16 + lh * 4 + r;
      const u64 wbits = dbits[((size_t)bb * SS + sr) * 32 + (n0 >> 6) + (lr & 3)];
      float z = 0.f;
#pragma unroll
      for (int nf = 0; nf < 4; ++nf) {
        const int tc = n0 + wn * 64 + nf * 16 + lr;
        float iv = isc[(size_t)sr * SS + tc];
        float sval = acc[mf][nf][r] * __builtin_amdgcn_rcpf(iv);
        float e = __expf(sval - MSHIFT);
        z += e;
        float pm = ((wbits >> (wn * 16 + nf * 4 + (lr >> 2))) & 1ull) ? (e * KEEPR) : 0.f;
        Pp[((size_t)(bb * 64 + (tc >> 5)) * SS + sr) * 32 + (tc & 31)] = f2bf(pm);
      }
#pragma unroll
      for (int off = 1; off < 16; off <<= 1) z += __shfl_xor(z, off);
      if (lr == 0) atomicAdd(&Z[bb * SS + sr], z);
    }
  }
}

// ---- pass 2: O = (P~ V) / Z. 128x128, 4 waves of 64x64, m-adjacent tile order ----
__global__ __launch_bounds__(256, 4)
void gemm_pv(const ushort* __restrict__ Pp, const ushort* __restrict__ Vp,
             const float* __restrict__ Z, float* __restrict__ out)
{
  const int bid = blockIdx.x;
  const int bb = bid & 7;
  const int tt = bid >> 3;                // 0..95
  const int m_idx = tt / 6;
  const int n_idx = tt - m_idx * 6;
  const int m0 = m_idx * 128;
  const int n0 = n_idx * 128;
  const int tid = threadIdx.x;
  const int w  = tid >> 6;
  const int l  = tid & 63;
  const int lr = l & 15;
  const int lh = l >> 4;
  const int wm = w & 1;
  const int wn = w >> 1;

  __shared__ __align__(16) char Plb[2][128][64];
  __shared__ __align__(16) char Vlb[2][128][64];

  const int srow = (w << 4) + (l >> 2);
  const size_t gc = (size_t)srow * 64 + (size_t)((((l & 3) ^ ((srow >> 1) & 3))) << 4);

  const char* gpb = (const char*)Pp + ((size_t)(bb * 64) * SS + m0) * 64;
  const char* gvb = (const char*)Vp + ((size_t)(bb * 64) * DD + n0) * 64;

  const f32x4 fzero = {0.f, 0.f, 0.f, 0.f};
  f32x4 acc[4][4];
#pragma unroll
  for (int mf = 0; mf < 4; ++mf)
#pragma unroll
    for (int nf = 0; nf < 4; ++nf) acc[mf][nf] = fzero;

#define PVSTAGE(t) do {                                                   \
    size_t k0 = (size_t)(t) * 2;                                          \
    gload16(gpb + k0 * (SS * 64) + gc,              &Plb[0][w << 4][0]);  \
    gload16(gpb + k0 * (SS * 64) + gc + 4096,       &Plb[0][(w << 4) + 64][0]); \
    gload16(gpb + (k0 + 1) * (SS * 64) + gc,        &Plb[1][w << 4][0]);  \
    gload16(gpb + (k0 + 1) * (SS * 64) + gc + 4096, &Plb[1][(w << 4) + 64][0]); \
    gload16(gvb + k0 * (DD * 64) + gc,              &Vlb[0][w << 4][0]);  \
    gload16(gvb + k0 * (DD * 64) + gc + 4096,       &Vlb[0][(w << 4) + 64][0]); \
    gload16(gvb + (k0 + 1) * (DD * 64) + gc,        &Vlb[1][w << 4][0]);  \
    gload16(gvb + (k0 + 1) * (DD * 64) + gc + 4096, &Vlb[1][(w << 4) + 64][0]); \
  } while (0)

  PVSTAGE(0);
  __syncthreads();
#pragma unroll 1
  for (int t = 0; t < 32; ++t) {
#pragma unroll
    for (int pk = 0; pk < 2; ++pk) {
      bf16x8 bfr[4];
#pragma unroll
      for (int nf = 0; nf < 4; ++nf) {
        int br = wn * 64 + nf * 16 + lr;
        int bo = (lh ^ ((br >> 1) & 3)) << 4;
        bfr[nf] = *(const bf16x8*)&Vlb[pk][br][bo];
      }
#pragma unroll
      for (int mf = 0; mf < 4; ++mf) {
        int ar = wm * 64 + mf * 16 + lr;
        int ao = (lh ^ ((ar >> 1) & 3)) << 4;
        bf16x8 af = *(const bf16x8*)&Plb[pk][ar][ao];
#pragma unroll
        for (int nf = 0; nf < 4; ++nf)
          acc[mf][nf] = __builtin_amdgcn_mfma_f32_16x16x32_bf16(af, bfr[nf], acc[mf][nf], 0, 0, 0);
      }
    }
    __syncthreads();
    if (t < 31) {
      PVSTAGE(t + 1);
      __syncthreads();
    }
  }
#undef PVSTAGE

#pragma unroll
  for (int mf = 0; mf < 4; ++mf) {
#pragma unroll
    for (int r = 0; r < 4; ++r) {
      const int sr = m0 + wm * 64 + mf * 16 + lh * 4 + r;
      float rz = __builtin_amdgcn_rcpf(Z[bb * SS + sr]);
#pragma unroll
      for (int nf = 0; nf < 4; ++nf) {
        const int dc = n0 + wn * 64 + nf * 16 + lr;
        out[((size_t)bb * SS + sr) * DD + dc] = acc[mf][nf][r] * rz;
      }
    }
  }
}

extern "C" void kernel_launch(void* const* d_in, const int* in_sizes, int n_in,
                              void* d_out, int out_size, void* d_ws, size_t ws_size,
                              hipStream_t stream) {
  const float* x1  = (const float*)d_in[0];
  const float* x2  = (const float*)d_in[1];
  const float* x3  = (const float*)d_in[2];
  const float* Wq  = (const float*)d_in[3];
  const float* bq  = (const float*)d_in[4];
  const float* Wk  = (const float*)d_in[5];
  const float* bk  = (const float*)d_in[6];
  const float* Wv  = (const float*)d_in[7];
  const float* bv  = (const float*)d_in[8];
  const float* isc = (const float*)d_in[9];
  const float* dmk = (const float*)d_in[10];
  float* out = (float*)d_out;

  const size_t QKN = (size_t)NB * 7 * SS * 32;        // 3.67M (f16)
  const size_t VPN = (size_t)NB * 64 * DD * 32;       // 12.6M (bf16)
  const size_t WN  = (size_t)WROWS * DD;
  const size_t NV  = (size_t)DD * DD;
  const size_t PPN = (size_t)NB * 64 * SS * 32;       // 33.5M (bf16)

  ushort* Qp  = (ushort*)d_ws;
  ushort* Kp  = Qp + QKN;
  ushort* Vp  = Kp + QKN;
  ushort* Wqp = Vp + VPN;
  ushort* Wkp = Wqp + WN;
  ushort* Wvb = Wkp + WN;
  ushort* Pp  = Wvb + NV;
  float*  Zb  = (float*)(Pp + PPN);                   // [8][2048]
  u64*    dbits = (u64*)(Zb + NB * SS);               // [8][2048][32] u64

  dim3 blk(256);
  prep_all<<<dim3(2048), blk, 0, stream>>>(dmk, Wq, Wk, Wv, dbits, Wqp, Wkp, Wvb, Zb);
  gemm_qk<<<dim3(256, 2), blk, 0, stream>>>(x1, x2, Wqp, Wkp, bq, bk, Qp, Kp);
  gemm_v <<<dim3(256, 3), blk, 0, stream>>>(x3, Wvb, bv, Vp);
  gemm_s <<<dim3(1024), dim3(512), 0, stream>>>(Qp, Kp, isc, dbits, Pp, Zb);
  gemm_pv<<<dim3(768),  dim3(256), 0, stream>>>(Pp, Vp, Zb, out);
}